// Round 7
// baseline (1278.635 us; speedup 1.0000x reference)
//
#include <hip/hip_runtime.h>

typedef __attribute__((ext_vector_type(8))) short bf16x8;
typedef __attribute__((ext_vector_type(4))) float f32x4;

#define NBLK 512
#define NTHR 1024   // 16 waves; 1 block/CU (128 KB LDS)
#define NT   4      // 16-row tiles per wave: 512 * 16 * 4 * 16 = 524288 rows
#define DOUT 128

__device__ __forceinline__ unsigned short bf_rne(float x) {
  unsigned u = __builtin_bit_cast(unsigned, x);
  return (unsigned short)((u + 0x7FFFu + ((u >> 16) & 1u)) >> 16);
}

// fp32 -> bf16 hi (truncate) + bf16 lo (RNE of residual); x ~ hi+lo to ~2^-15 rel
__device__ __forceinline__ void split2(float x, short& hi, short& lo) {
  unsigned u = __builtin_bit_cast(unsigned, x);
  float hf = __builtin_bit_cast(float, u & 0xFFFF0000u);
  hi = (short)(unsigned short)(u >> 16);
  lo = (short)bf_rne(x - hf);
}

// Autonomous-wave design (R6 structure, spill-fixed):
//  - masked+split weights staged to LDS ONCE (128 KB), zero main-loop barriers
//  - x streamed via 4-deep per-lane register prefetch (static ks&3 indexing)
//  - launch_bounds(1024) ONLY: 1024-thread groups force VGPR<=128; the 2nd arg
//    empirically caps VGPR at 256/arg (R3: (512,8)->32, R4: (512,4)->64,
//    R6: (1024,4)->64 + 1.7 GB scratch spill). Do not pass a 2nd arg.
//  - MFMA operands SWAPPED vs R1-R5 (W as A, x as B): same fragments, but
//    D gives lane=batch-row, regs=4 contiguous cols -> f32x4 C-stores.
__global__ __launch_bounds__(NTHR)
void dagmm(const float* __restrict__ x0, const float* __restrict__ x1,
           const float* __restrict__ w0, const float* __restrict__ w1,
           const float* __restrict__ m0, const float* __restrict__ m1,
           float* __restrict__ out)
{
  __shared__ short wl[65536];   // 128 KB masked+split weights

  const int t   = threadIdx.x;
  const int l   = t & 63;
  const int w   = t >> 6;       // wave 0..15
  const int l16 = l & 15;
  const int lq  = l >> 4;

  // ---------- stage masked, hi/lo-split weights into LDS (once) ----------
  // layout: cix = ct*8+ks; hi bf16x8 at short-idx cix*1024 + lane*8, lo at +512.
  // lane holds W[col=ct*16+(l&15)][k=ks*32+(l>>4)*8+j]  == A-frag for 16x16x32.
#pragma unroll
  for (int rep = 0; rep < 4; ++rep) {
    const int chunk = rep * 1024 + t;          // 4096 = 64 cix * 64 lanes
    const int cl  = chunk & 63;
    const int cks = (chunk >> 6) & 7;
    const int cct = (chunk >> 9) & 7;
    const int col = cct * 16 + (cl & 15);
    const int k0  = cks * 32 + ((cl >> 4) << 3);   // 0..248, never straddles 128
    const float* wp = (k0 < 128) ? (w0 + col * 128 + k0) : (w1 + col * 128 + (k0 - 128));
    const float* mp = (k0 < 128) ? (m0 + col * 128 + k0) : (m1 + col * 128 + (k0 - 128));
    float4 wa = *(const float4*)wp, wb = *(const float4*)(wp + 4);
    float4 ma = *(const float4*)mp, mb = *(const float4*)(mp + 4);
    float v[8] = {wa.x*ma.x, wa.y*ma.y, wa.z*ma.z, wa.w*ma.w,
                  wb.x*mb.x, wb.y*mb.y, wb.z*mb.z, wb.w*mb.w};
    bf16x8 hv, lv;
#pragma unroll
    for (int j = 0; j < 8; ++j) { short h, lo2; split2(v[j], h, lo2); hv[j] = h; lv[j] = lo2; }
    const int base = (cct * 8 + cks) * 1024 + cl * 8;
    *(bf16x8*)&wl[base]       = hv;
    *(bf16x8*)&wl[base + 512] = lv;
  }
  __syncthreads();   // only barrier in the kernel

  const int gw = blockIdx.x * 16 + w;   // owns rows [gw*64, gw*64+64)

  // x address for (tile tt, k-step ks): lane reads 8 consecutive floats
  // (row = base + l16, k = ks*32 + lq*8) — the 16x16x32 B-fragment.
  auto xaddr = [&](int tt, int ks) -> const float* {
    const int k = ks * 32 + lq * 8;     // 0..248, never straddles 128
    const float* bp = (k < 128) ? (x0 + k) : (x1 + (k - 128));
    return bp + (size_t)(gw * 64 + tt * 16 + l16) * 128;
  };

  // 4-deep prefetch slots, statically indexed by ks&3 after unroll
  float4 pf[4][2];
#pragma unroll
  for (int s = 0; s < 4; ++s) {
    const float* p = xaddr(0, s);
    pf[s][0] = *(const float4*)p;
    pf[s][1] = *(const float4*)(p + 4);
  }

  for (int tt = 0; tt < NT; ++tt) {
    f32x4 acc[8];
#pragma unroll
    for (int ct = 0; ct < 8; ++ct) acc[ct] = (f32x4){0.f, 0.f, 0.f, 0.f};

#pragma unroll
    for (int ks = 0; ks < 8; ++ks) {
      const int sl = ks & 3;
      float4 c0 = pf[sl][0], c1 = pf[sl][1];

      // refill slot with step (tt*8 + ks + 4)
      if (ks < 4) {                       // static: same tile
        const float* np = xaddr(tt, ks + 4);
        pf[sl][0] = *(const float4*)np;
        pf[sl][1] = *(const float4*)(np + 4);
      } else if (tt + 1 < NT) {           // wave-uniform branch: next tile
        const float* np = xaddr(tt + 1, ks - 4);
        pf[sl][0] = *(const float4*)np;
        pf[sl][1] = *(const float4*)(np + 4);
      }

      float vv[8] = {c0.x, c0.y, c0.z, c0.w, c1.x, c1.y, c1.z, c1.w};
      bf16x8 xh, xl;
#pragma unroll
      for (int j = 0; j < 8; ++j) { short h, lo2; split2(vv[j], h, lo2); xh[j] = h; xl[j] = lo2; }

#pragma unroll
      for (int ct = 0; ct < 8; ++ct) {
        const int bi = (ct * 8 + ks) * 1024 + l * 8;
        bf16x8 wh  = *(const bf16x8*)&wl[bi];
        bf16x8 wlo = *(const bf16x8*)&wl[bi + 512];
        // W ~ wh+wlo, X ~ xh+xl:  wh*xh + wh*xl + wlo*xh  (drop wlo*xl ~2^-30)
        acc[ct] = __builtin_amdgcn_mfma_f32_16x16x32_bf16(wh,  xh, acc[ct], 0, 0, 0);
        acc[ct] = __builtin_amdgcn_mfma_f32_16x16x32_bf16(wh,  xl, acc[ct], 0, 0, 0);
        acc[ct] = __builtin_amdgcn_mfma_f32_16x16x32_bf16(wlo, xh, acc[ct], 0, 0, 0);
      }
    }

    // D (swapped): col(lane&15) = batch row, row(lq*4+reg) = output col
    // -> each lane stores 4 contiguous cols as one f32x4.
    const size_t row = (size_t)gw * 64 + tt * 16 + l16;
#pragma unroll
    for (int ct = 0; ct < 8; ++ct)
      *(f32x4*)&out[row * DOUT + ct * 16 + lq * 4] = acc[ct];
  }
}

extern "C" void kernel_launch(void* const* d_in, const int* in_sizes, int n_in,
                              void* d_out, int out_size, void* d_ws, size_t ws_size,
                              hipStream_t stream) {
  const float* x0 = (const float*)d_in[0];
  const float* x1 = (const float*)d_in[1];
  const float* w0 = (const float*)d_in[2];
  const float* w1 = (const float*)d_in[3];
  const float* m0 = (const float*)d_in[4];
  const float* m1 = (const float*)d_in[5];
  dagmm<<<NBLK, NTHR, 0, stream>>>(x0, x1, w0, w1, m0, m1, (float*)d_out);
}

// Round 8
// 213.330 us; speedup vs baseline: 5.9937x; 5.9937x over previous
//
#include <hip/hip_runtime.h>

typedef __attribute__((ext_vector_type(8))) short bf16x8;
typedef __attribute__((ext_vector_type(4))) float f32x4;

#define NBLK 1024
#define NTHR 512    // 8 waves; 1 block/CU (128 KB LDS), 8 autonomous waves
#define DOUT 128

__device__ __forceinline__ unsigned short bf_rne(float x) {
  unsigned u = __builtin_bit_cast(unsigned, x);
  return (unsigned short)((u + 0x7FFFu + ((u >> 16) & 1u)) >> 16);
}

// fp32 -> bf16 hi (truncate) + bf16 lo (RNE of residual); x ~ hi+lo to ~2^-15 rel
__device__ __forceinline__ void split2(float x, short& hi, short& lo) {
  unsigned u = __builtin_bit_cast(unsigned, x);
  float hf = __builtin_bit_cast(float, u & 0xFFFF0000u);
  hi = (short)(unsigned short)(u >> 16);
  lo = (short)bf_rne(x - hf);
}

// Autonomous-wave design, register-budget-fixed.
// gfx950 empirical register law (R1-R7): with MFMA/AGPRs in use, total budget
// = 512/(waves_per_eu arg), arch-VGPR cap = budget/2:
//   (256,2)->128V, (512,4)->64V, (512,8)->32V, 1024-thr any -> 64V (+spill).
// => 1024-thread blocks can NEVER exceed 64 arch VGPRs; this body needs ~105.
// (512,2): budget 256 -> 128 V + 128 AGPR. 8 waves/block, 1 block/CU.
//  - masked+split weights staged to LDS ONCE (128 KB), zero main-loop barriers
//  - per wave: 64 rows as 2 tiles x 32 rows; 16 fully-unrolled k-steps
//  - depth-3 prefetch slots (s%3 static after unroll), issued ~3 steps (~870cy)
//    ahead of use ~= HBM latency
//  - MFMA swapped (W=A, x=B): lane stores f32x4 of 4 contiguous out cols
//    (mapping verified by R7 pass, absmax 0.015625)
__global__ __launch_bounds__(NTHR, 2)
void dagmm(const float* __restrict__ x0, const float* __restrict__ x1,
           const float* __restrict__ w0, const float* __restrict__ w1,
           const float* __restrict__ m0, const float* __restrict__ m1,
           float* __restrict__ out)
{
  __shared__ short wl[65536];   // 128 KB masked+split weights

  const int t   = threadIdx.x;
  const int l   = t & 63;
  const int w   = t >> 6;       // wave 0..7
  const int l16 = l & 15;
  const int lq  = l >> 4;

  // ---------- stage masked, hi/lo-split weights into LDS (once) ----------
  // layout: cix = ct*8+ks; hi bf16x8 at short-idx cix*1024 + lane*8, lo at +512.
  // lane holds W[col=ct*16+(l&15)][k=ks*32+(l>>4)*8+j]  == A-frag for 16x16x32.
#pragma unroll
  for (int rep = 0; rep < 8; ++rep) {
    const int chunk = rep * 512 + t;           // 4096 = 64 cix * 64 lanes
    const int cl  = chunk & 63;
    const int cks = (chunk >> 6) & 7;
    const int cct = (chunk >> 9) & 7;
    const int col = cct * 16 + (cl & 15);
    const int k0  = cks * 32 + ((cl >> 4) << 3);   // 0..248, never straddles 128
    const float* wp = (k0 < 128) ? (w0 + col * 128 + k0) : (w1 + col * 128 + (k0 - 128));
    const float* mp = (k0 < 128) ? (m0 + col * 128 + k0) : (m1 + col * 128 + (k0 - 128));
    float4 wa = *(const float4*)wp, wb = *(const float4*)(wp + 4);
    float4 ma = *(const float4*)mp, mb = *(const float4*)(mp + 4);
    float v[8] = {wa.x*ma.x, wa.y*ma.y, wa.z*ma.z, wa.w*ma.w,
                  wb.x*mb.x, wb.y*mb.y, wb.z*mb.z, wb.w*mb.w};
    bf16x8 hv, lv;
#pragma unroll
    for (int j = 0; j < 8; ++j) { short h, lo2; split2(v[j], h, lo2); hv[j] = h; lv[j] = lo2; }
    const int base = (cct * 8 + cks) * 1024 + cl * 8;
    *(bf16x8*)&wl[base]       = hv;
    *(bf16x8*)&wl[base + 512] = lv;
  }
  __syncthreads();   // only barrier in the kernel

  const int gw = blockIdx.x * 8 + w;   // owns rows [gw*64, gw*64+64)

  // x address for step s (tt = s>>3 tile, ks = s&7) and row-half rt:
  // lane reads 8 floats at (row = gw*64 + tt*32 + rt*16 + l16, k = ks*32+lq*8)
  auto xaddr = [&](int s, int rt) -> const float* {
    const int k = (s & 7) * 32 + lq * 8;     // 0..248, never straddles 128
    const float* bp = (k < 128) ? (x0 + k) : (x1 + (k - 128));
    return bp + (size_t)(gw * 64 + (s >> 3) * 32 + rt * 16 + l16) * 128;
  };

  // depth-3 prefetch slots: [slot][rt*2 + half]
  float4 pf[3][4];
#pragma unroll
  for (int s = 0; s < 3; ++s) {
    const float* p0 = xaddr(s, 0);
    const float* p1 = xaddr(s, 1);
    pf[s][0] = *(const float4*)p0; pf[s][1] = *(const float4*)(p0 + 4);
    pf[s][2] = *(const float4*)p1; pf[s][3] = *(const float4*)(p1 + 4);
  }

  f32x4 acc[2][8];   // [rt][ct] -> 64 AGPRs
#pragma unroll
  for (int rt = 0; rt < 2; ++rt)
#pragma unroll
    for (int ct = 0; ct < 8; ++ct) acc[rt][ct] = (f32x4){0.f, 0.f, 0.f, 0.f};

#pragma unroll
  for (int s = 0; s < 16; ++s) {
    const int sl = s % 3;                  // static after unroll
    float4 a0 = pf[sl][0], a1 = pf[sl][1]; // rt0: 8 floats
    float4 b0 = pf[sl][2], b1 = pf[sl][3]; // rt1: 8 floats

    if (s + 3 < 16) {                      // refill slot for step s+3 (static)
      const float* p0 = xaddr(s + 3, 0);
      const float* p1 = xaddr(s + 3, 1);
      pf[sl][0] = *(const float4*)p0; pf[sl][1] = *(const float4*)(p0 + 4);
      pf[sl][2] = *(const float4*)p1; pf[sl][3] = *(const float4*)(p1 + 4);
    }

    bf16x8 xh0, xl0, xh1, xl1;
    {
      float va[8] = {a0.x, a0.y, a0.z, a0.w, a1.x, a1.y, a1.z, a1.w};
      float vb[8] = {b0.x, b0.y, b0.z, b0.w, b1.x, b1.y, b1.z, b1.w};
#pragma unroll
      for (int j = 0; j < 8; ++j) {
        short h, lo2;
        split2(va[j], h, lo2); xh0[j] = h; xl0[j] = lo2;
        split2(vb[j], h, lo2); xh1[j] = h; xl1[j] = lo2;
      }
    }

    const int ks = s & 7;
#pragma unroll
    for (int ct = 0; ct < 8; ++ct) {
      const int bi = (ct * 8 + ks) * 1024 + l * 8;
      bf16x8 wh  = *(const bf16x8*)&wl[bi];
      bf16x8 wlo = *(const bf16x8*)&wl[bi + 512];
      // W ~ wh+wlo, X ~ xh+xl: wh*xh + wh*xl + wlo*xh (drop wlo*xl ~2^-30)
      acc[0][ct] = __builtin_amdgcn_mfma_f32_16x16x32_bf16(wh,  xh0, acc[0][ct], 0, 0, 0);
      acc[0][ct] = __builtin_amdgcn_mfma_f32_16x16x32_bf16(wh,  xl0, acc[0][ct], 0, 0, 0);
      acc[0][ct] = __builtin_amdgcn_mfma_f32_16x16x32_bf16(wlo, xh0, acc[0][ct], 0, 0, 0);
      acc[1][ct] = __builtin_amdgcn_mfma_f32_16x16x32_bf16(wh,  xh1, acc[1][ct], 0, 0, 0);
      acc[1][ct] = __builtin_amdgcn_mfma_f32_16x16x32_bf16(wh,  xl1, acc[1][ct], 0, 0, 0);
      acc[1][ct] = __builtin_amdgcn_mfma_f32_16x16x32_bf16(wlo, xh1, acc[1][ct], 0, 0, 0);
    }

    if ((s & 7) == 7) {                    // end of tile tt = s>>3 (static)
      const int tt = s >> 3;
      // D (swapped): col(l16) = x-row, row(lq*4+r) = out col -> f32x4 stores
#pragma unroll
      for (int rt = 0; rt < 2; ++rt) {
        const size_t row = (size_t)gw * 64 + tt * 32 + rt * 16 + l16;
#pragma unroll
        for (int ct = 0; ct < 8; ++ct) {
          *(f32x4*)&out[row * DOUT + ct * 16 + lq * 4] = acc[rt][ct];
          acc[rt][ct] = (f32x4){0.f, 0.f, 0.f, 0.f};
        }
      }
    }
  }
}

extern "C" void kernel_launch(void* const* d_in, const int* in_sizes, int n_in,
                              void* d_out, int out_size, void* d_ws, size_t ws_size,
                              hipStream_t stream) {
  const float* x0 = (const float*)d_in[0];
  const float* x1 = (const float*)d_in[1];
  const float* w0 = (const float*)d_in[2];
  const float* w1 = (const float*)d_in[3];
  const float* m0 = (const float*)d_in[4];
  const float* m1 = (const float*)d_in[5];
  dagmm<<<NBLK, NTHR, 0, stream>>>(x0, x1, w0, w1, m0, m1, (float*)d_out);
}